// Round 17
// baseline (71.067 us; speedup 1.0000x reference)
//
#include <hip/hip_runtime.h>
#include <stdint.h>

namespace {

constexpr int   B_   = 64;
constexpr int   F0_  = 1876;
constexpr int   F0P_ = 1880;      // padded rec length (pads never processed)
constexpr int   NI4_ = 469;       // 1876 / 4 exact
constexpr int   F1_  = 1024;
constexpr int   F2_  = 10;
constexpr int   NT_  = 151;
constexpr float DT_  = 0.02f;
constexpr float SCL_  = 1073741824.0f;      // 2^30 fixed-point scale
constexpr float ISCL_ = 1.0f / 1073741824.0f;

constexpr int NBLK_T = 480;       // 30 i-tiles x 16 j-tiles
constexpr int NBLK_R = 470;       // 64*1880/256 exact

// workspace layout (bytes)
constexpr size_t OFF_W1I4 = 0;                     // 469*1024*16 = 7,684,096
constexpr size_t OFF_KOFF = 7684096;               // 64*1880*2   =   240,640
constexpr size_t OFF_TV   = 7924736;               // 64*1880*4   =   481,280
constexpr size_t OFF_IDX1 = 8406016;               // 64*1024 u8  =    65,536

// ---------------------------------------------------------------------------
// k_prep: (a) blocks < 480:  W1[j][i] f32 -> W1iT4[i4][j][4] int
//             (int4 per (i4,j): 4 consecutive i's weights, rn(w*2^30))
//         (b) blocks >= 480: koff16[b][i] = clamp(ceil(ti*50),0,50)*256 (u16,
//             bins row stride 32*8 = 256 B); tvarr[b][i] = ti.
// ---------------------------------------------------------------------------
__global__ __launch_bounds__(256) void k_prep(const float* __restrict__ W1,
                                              const float* __restrict__ ti,
                                              int4* __restrict__ W1iT4,
                                              uint16_t* __restrict__ koff16,
                                              float* __restrict__ tvarr) {
  const int t = threadIdx.x;
  if (blockIdx.x < NBLK_T) {
    __shared__ float tile[64][65];
    const int bx = blockIdx.x;
    const int i0 = (bx % 30) * 64;     // 0..1856
    const int j0 = (bx / 30) * 64;
    const int c = t & 63, r4 = t >> 6;
    for (int jj = r4; jj < 64; jj += 4) {
      int i = i0 + c;
      tile[c][jj] = (i < F0_) ? W1[(size_t)(j0 + jj) * F0_ + i] : 0.0f;
    }
    __syncthreads();
    for (int ii4 = r4; ii4 < 16; ii4 += 4) {
      int i4 = (i0 >> 2) + ii4;
      if (i4 < NI4_) {
        int4 v;
        v.x = __float2int_rn(tile[ii4 * 4 + 0][c] * SCL_);
        v.y = __float2int_rn(tile[ii4 * 4 + 1][c] * SCL_);
        v.z = __float2int_rn(tile[ii4 * 4 + 2][c] * SCL_);
        v.w = __float2int_rn(tile[ii4 * 4 + 3][c] * SCL_);
        W1iT4[(size_t)i4 * F1_ + j0 + c] = v;
      }
    }
  } else {
    int n = (blockIdx.x - NBLK_T) * 256 + t;     // < 120,320
    int b = n / F0P_, i = n - b * F0P_;
    if (i < F0_) {
      float v = ti[(size_t)b * F0_ + i];
      int k = (int)fminf(ceilf(v * 50.0f), 50.0f);   // ti >= 0 -> k >= 0
      koff16[n] = (uint16_t)(k << 8);                // k*256
      tvarr[n]  = v;
    } else {
      koff16[n] = 0;
      tvarr[n]  = 0.0f;                              // pads never processed
    }
  }
}

// ---------------------------------------------------------------------------
// Layer 1: 2048 blocks = b*32 + jg (XCD = blk%8 -> 4 W slices ~1 MB, L2-fit),
// 512 threads = 8 waves; thread = (isub = tid>>5 in 0..15, jl = tid&31).
// Thread streams i4 = isub, isub+16, ... — waves split i 16 ways.
// r16 lesson: grid 1024 = exactly-one-batch -> Occupancy 49%, latency
// exposed.  2048 finer blocks give 4 resident + 4 QUEUED per CU so the
// scheduler backfills as waves drain (r12-r14 measured 81-85% at 4096).
// Wave-level ds_add_u64: 2 bin-rows x 32 jl = 64 distinct addresses,
// 4 touches/bank = u64 floor -> conflict-free by construction (r15/r16: 0).
// Packed pk = (a<<32)|(c mod 2^32), int adds commute -> bit-deterministic;
// borrow-corrected unpack exact (absmax 0.0 in r13-r16).
// Phase 2: tid<32 fused per-bin unpack + prefix + first-crossing scan.
// LDS 24.3 KB.
// ---------------------------------------------------------------------------
__global__ __launch_bounds__(512, 8) void k_main1(const uint16_t* __restrict__ koff16,
                                                  const float* __restrict__ tvarr,
                                                  const int4* __restrict__ W1iT4,
                                                  uint8_t* __restrict__ idx1) {
  __shared__ unsigned long long bins[51][32];    // 13,056 B
  __shared__ uint16_t lkoff[F0P_];               //  3,760 B
  __shared__ float    ltv[F0P_];                 //  7,520 B
  const int blk  = blockIdx.x;        // 2048
  const int b    = blk >> 5;
  const int jg   = blk & 31;
  const int tid  = threadIdx.x;
  const int jl   = tid & 31;
  const int isub = tid >> 5;          // 0..15

  {
    int4* p = (int4*)(&bins[0][0]);
    for (int s = tid; s < (int)(sizeof(bins) / 16); s += 512)
      p[s] = make_int4(0, 0, 0, 0);
    const uint32_t* ks = (const uint32_t*)(koff16 + (size_t)b * F0P_);
    uint32_t* kd = (uint32_t*)lkoff;
    for (int s = tid; s < F0P_ / 2; s += 512) kd[s] = ks[s];
    const float* ts = tvarr + (size_t)b * F0P_;
    for (int s = tid; s < F0P_; s += 512) ltv[s] = ts[s];
  }
  __syncthreads();

  const int4* __restrict__ wp = W1iT4 + (jg << 5) + jl;   // + i4*1024
  char* const binlane = (char*)(&bins[0][0]) + (jl << 3);

#define ELEM(a_, tv_, ko_) {                                                  \
    int   c_ = __float2int_rn((float)(a_) * (tv_));                           \
    unsigned long long pk =                                                   \
        ((unsigned long long)(unsigned)(a_) << 32) | (unsigned)(c_);          \
    atomicAdd((unsigned long long*)(binlane + (ko_)), pk); }

#pragma unroll 2
  for (int i4 = isub; i4 < NI4_; i4 += 16) {
    int4   wa  = wp[(size_t)i4 << 10];                 // 2 x 512 B / wave
    uint2  kk  = *(const uint2*)(lkoff + i4 * 4);      // 2-way LDS broadcast
    float4 tv4 = *(const float4*)(ltv + i4 * 4);
    ELEM(wa.x, tv4.x, kk.x & 0xFFFFu);
    ELEM(wa.y, tv4.y, kk.x >> 16);
    ELEM(wa.z, tv4.z, kk.y & 0xFFFFu);
    ELEM(wa.w, tv4.w, kk.y >> 16);
  }
#undef ELEM
  __syncthreads();

  // phase 2: tid < 32, thread owns j = jg*32 + jl.
  if (tid < 32) {
    float sa = 0.f, sc = 0.f;
    int cnd = NT_;
#pragma unroll 1
    for (int tt = 0; tt < NT_; ++tt) {
      if (tt < 51) {
        unsigned long long s = bins[tt][tid];
        int cl = (int)(unsigned)(s & 0xFFFFFFFFull);
        int ah = (int)(unsigned)(s >> 32);
        if (cl < 0) ah += 1;                   // borrow correction (exact)
        sa += (float)ah * ISCL_;
        sc += (float)cl * ISCL_;
      }
      float mv = (float)tt * DT_ * sa - sc;
      if (cnd == NT_ && mv >= 1.0f) cnd = tt;
    }
    cnd = min(cnd, NT_ - 1);                   // forced spike at last step
    idx1[((size_t)b << 10) + (jg << 5) + tid] = (uint8_t)cnd;
  }
}

// ---------------------------------------------------------------------------
// Layer-2: brute force. Block = (b,j), 4 waves split the i-range; lane = t.
// (unchanged, proven)
// ---------------------------------------------------------------------------
__global__ __launch_bounds__(256) void k_main2(const uint8_t* __restrict__ idx1,
                                               const float* __restrict__ W2,
                                               float* __restrict__ out) {
  __shared__ float wrow[F1_];
  __shared__ float tirow[F1_];
  __shared__ float part[4][3][64];
  const int blk = blockIdx.x;          // 640
  const int b   = blk / 10;
  const int j   = blk - b * 10;
  const int tid = threadIdx.x;
  const int lane = tid & 63, wvv = tid >> 6;

  const float*   w = W2  + (size_t)j * F1_;
  const uint8_t* h = idx1 + (size_t)b * F1_;
  for (int s = tid; s < F1_; s += 256) {
    wrow[s]  = w[s];
    tirow[s] = (float)h[s] * DT_;
  }
  __syncthreads();

  const float tl0 = (float)lane * DT_;
  const float tl1 = (float)(lane + 64) * DT_;
  const float tl2 = (float)(lane + 128) * DT_;
  float m0 = 0.f, m1 = 0.f, m2 = 0.f;
  const int i0 = wvv * 256;
#pragma unroll 4
  for (int i = i0; i < i0 + 256; ++i) {
    float tiv = tirow[i], ww = wrow[i];
    m0 = fmaf(ww, fmaxf(tl0 - tiv, 0.f), m0);
    m1 = fmaf(ww, fmaxf(tl1 - tiv, 0.f), m1);
    m2 = fmaf(ww, fmaxf(tl2 - tiv, 0.f), m2);
  }
  part[wvv][0][lane] = m0;
  part[wvv][1][lane] = m1;
  part[wvv][2][lane] = m2;
  __syncthreads();

  if (wvv == 0) {
    m0 = part[0][0][lane] + part[1][0][lane] + part[2][0][lane] + part[3][0][lane];
    m1 = part[0][1][lane] + part[1][1][lane] + part[2][1][lane] + part[3][1][lane];
    m2 = part[0][2][lane] + part[1][2][lane] + part[2][2][lane] + part[3][2][lane];
    unsigned long long b0 = __ballot(m0 >= 1.0f);
    unsigned long long b1 = __ballot(m1 >= 1.0f);
    unsigned long long b2 = __ballot(m2 >= 1.0f);
    b2 &= (1ull << 23) - 1;            // t <= 150
    b2 |= (1ull << 22);                // forced spike at t = 150
    int tres;
    if (b0)      tres = __ffsll((long long)b0) - 1;
    else if (b1) tres = 64 + __ffsll((long long)b1) - 1;
    else         tres = 128 + __ffsll((long long)b2) - 1;
    if (lane == 0) out[(size_t)b * F2_ + j] = (float)tres * DT_;
  }
}

}  // namespace

// ---------------------------------------------------------------------------
extern "C" void kernel_launch(void* const* d_in, const int* in_sizes, int n_in,
                              void* d_out, int out_size, void* d_ws, size_t ws_size,
                              hipStream_t stream) {
  const float* ti = (const float*)d_in[0];   // [64][1876]
  const float* W1 = (const float*)d_in[1];   // [1024][1876]
  const float* W2 = (const float*)d_in[2];   // [10][1024]
  float* out = (float*)d_out;                // [64][10]

  char* ws = (char*)d_ws;
  int4*     W1iT4 = (int4*)(ws + OFF_W1I4);
  uint16_t* koff  = (uint16_t*)(ws + OFF_KOFF);
  float*    tvs   = (float*)(ws + OFF_TV);
  uint8_t*  idx1  = (uint8_t*)(ws + OFF_IDX1);

  hipLaunchKernelGGL(k_prep,  dim3(NBLK_T + NBLK_R), dim3(256), 0, stream,
                     W1, ti, W1iT4, koff, tvs);
  hipLaunchKernelGGL(k_main1, dim3(2048), dim3(512), 0, stream,
                     koff, tvs, W1iT4, idx1);
  hipLaunchKernelGGL(k_main2, dim3(640),  dim3(256), 0, stream, idx1, W2, out);
}

// Round 19
// 69.295 us; speedup vs baseline: 1.0256x; 1.0256x over previous
//
#include <hip/hip_runtime.h>
#include <stdint.h>

namespace {

constexpr int   B_   = 64;
constexpr int   F0_  = 1876;
constexpr int   F0P_ = 1880;      // padded rec length (pads never processed)
constexpr int   NI4_ = 469;       // 1876 / 4 exact
constexpr int   F1_  = 1024;
constexpr int   F2_  = 10;
constexpr int   NT_  = 151;
constexpr float DT_  = 0.02f;
constexpr float SCL_  = 1073741824.0f;      // 2^30 fixed-point scale
constexpr float ISCL_ = 1.0f / 1073741824.0f;

constexpr int NBLK_T = 480;       // 30 i-tiles x 16 j-tiles
constexpr int NBLK_R = 470;       // 64*1880/256 exact

// workspace layout (bytes)
constexpr size_t OFF_W1I4 = 0;                     // 469*1024*16 = 7,684,096
constexpr size_t OFF_KOFF = 7684096;               // 64*1880*2   =   240,640
constexpr size_t OFF_TV   = 7924736;               // 64*1880*4   =   481,280
constexpr size_t OFF_IDX1 = 8406016;               // 64*1024 u8  =    65,536

// ---------------------------------------------------------------------------
// k_prep: (a) blocks < 480:  W1[j][i] f32 -> W1iT4[i4][j][4] int
//             (int4 per (i4,j): 4 consecutive i's weights, rn(w*2^30))
//         (b) blocks >= 480: koff16[b][i] = clamp(ceil(ti*50),0,50)*256 (u16,
//             bins row stride 64*4 = 256 B); tvarr[b][i] = ti.
// ---------------------------------------------------------------------------
__global__ __launch_bounds__(256) void k_prep(const float* __restrict__ W1,
                                              const float* __restrict__ ti,
                                              int4* __restrict__ W1iT4,
                                              uint16_t* __restrict__ koff16,
                                              float* __restrict__ tvarr) {
  const int t = threadIdx.x;
  if (blockIdx.x < NBLK_T) {
    __shared__ float tile[64][65];
    const int bx = blockIdx.x;
    const int i0 = (bx % 30) * 64;     // 0..1856
    const int j0 = (bx / 30) * 64;
    const int c = t & 63, r4 = t >> 6;
    for (int jj = r4; jj < 64; jj += 4) {
      int i = i0 + c;
      tile[c][jj] = (i < F0_) ? W1[(size_t)(j0 + jj) * F0_ + i] : 0.0f;
    }
    __syncthreads();
    for (int ii4 = r4; ii4 < 16; ii4 += 4) {
      int i4 = (i0 >> 2) + ii4;
      if (i4 < NI4_) {
        int4 v;
        v.x = __float2int_rn(tile[ii4 * 4 + 0][c] * SCL_);
        v.y = __float2int_rn(tile[ii4 * 4 + 1][c] * SCL_);
        v.z = __float2int_rn(tile[ii4 * 4 + 2][c] * SCL_);
        v.w = __float2int_rn(tile[ii4 * 4 + 3][c] * SCL_);
        W1iT4[(size_t)i4 * F1_ + j0 + c] = v;
      }
    }
  } else {
    int n = (blockIdx.x - NBLK_T) * 256 + t;     // < 120,320
    int b = n / F0P_, i = n - b * F0P_;
    if (i < F0_) {
      float v = ti[(size_t)b * F0_ + i];
      int k = (int)fminf(ceilf(v * 50.0f), 50.0f);   // ti >= 0 -> k >= 0
      koff16[n] = (uint16_t)(k << 8);                // k*256
      tvarr[n]  = v;
    } else {
      koff16[n] = 0;
      tvarr[n]  = 0.0f;                              // pads never processed
    }
  }
}

// ---------------------------------------------------------------------------
// Layer 1: 1024 blocks = b*16 + jg (XCD = jg%8 -> ~1 MB W slice L2-fit),
// 512 threads = 8 waves; wave = 64 lanes = 64 j (lane = j); waves split the
// 469-i4 range 8 ways.  Rec stream (koff,tv) is WAVE-UNIFORM per i4 -> read
// straight from global (broadcast), no LDS staging.  Atomics: per element
// TWO ds_add_u32 (each stride-1 32-bit = 2 touches/bank free-tier) instead
// of one ds_add_u64 (4 touches/bank RMW) — A/B on the r16/r17 finding that
// the wall == DS-atomic throughput.  r18 BUG FIX: bins is ONE shared array
// (bins[2][51][64]); r18 used two separate __shared__ arrays addressed by
// cross-array pointer offset — LDS allocation order is NOT guaranteed, so
// binC writes/init corrupted (absmax 0.24).  Within-array +13056 is legal
// and folds into the ds offset immediate.
// int32 adds commute -> bit-deterministic; |per-cell sums| < 2^31 (proven,
// absmax 0.0 r13-r17).  Phase 2: tid<64 fused prefix+crossing. LDS 26 KB.
// ---------------------------------------------------------------------------
__global__ __launch_bounds__(512, 8) void k_main1(const uint16_t* __restrict__ koff16,
                                                  const float* __restrict__ tvarr,
                                                  const int4* __restrict__ W1iT4,
                                                  uint8_t* __restrict__ idx1) {
  __shared__ int bins[2][51][64];   // [0]=A, [1]=C — contiguous by construction
  const int blk  = blockIdx.x;      // 1024
  const int b    = blk >> 4;
  const int jg   = blk & 15;
  const int tid  = threadIdx.x;
  const int lane = tid & 63;
  const int wv   = __builtin_amdgcn_readfirstlane(tid >> 6);  // 0..7

  {
    int4* p = (int4*)(&bins[0][0][0]);
    for (int s = tid; s < (2 * 51 * 64) / 4; s += 512)
      p[s] = make_int4(0, 0, 0, 0);
  }
  __syncthreads();

  // wave i4-split: 469 = 8*58 + 5
  const int cnt = 58 + (wv < 5 ? 1 : 0);
  const int g0  = wv * 58 + (wv < 5 ? wv : 5);

  const int4*     __restrict__ wp = W1iT4 + (jg << 6) + lane;  // + i4*1024
  const uint16_t* __restrict__ kb = koff16 + (size_t)b * F0P_; // uniform
  const float*    __restrict__ tb = tvarr  + (size_t)b * F0P_; // uniform
  char* const binlane = (char*)(&bins[0][0][0]) + (lane << 2);

#define ELEM(a_, tv_, ko_) {                                                  \
    int c_ = __float2int_rn((float)(a_) * (tv_));                             \
    int* cell = (int*)(binlane + (ko_));                                      \
    atomicAdd(cell, (a_));                  /* ds_add_u32, binA */            \
    atomicAdd(cell + 51 * 64, c_);          /* binC: +13056 B, same array */ }

#pragma unroll 2
  for (int m = 0; m < cnt; ++m) {
    const int i4 = g0 + m;
    int4   wa  = wp[(size_t)i4 << 10];              // coalesced 1 KB/wave
    uint2  kk  = *(const uint2*)(kb + i4 * 4);      // uniform broadcast
    float4 tv4 = *(const float4*)(tb + i4 * 4);     // uniform broadcast
    ELEM(wa.x, tv4.x, kk.x & 0xFFFFu);
    ELEM(wa.y, tv4.y, kk.x >> 16);
    ELEM(wa.z, tv4.z, kk.y & 0xFFFFu);
    ELEM(wa.w, tv4.w, kk.y >> 16);
  }
#undef ELEM
  __syncthreads();

  // phase 2: tid < 64, thread owns j = jg*64 + tid. Fused prefix + crossing.
  if (tid < 64) {
    float sa = 0.f, sc = 0.f;
    int cnd = NT_;
#pragma unroll 1
    for (int tt = 0; tt < NT_; ++tt) {
      if (tt < 51) {
        sa += (float)bins[0][tt][tid] * ISCL_;
        sc += (float)bins[1][tt][tid] * ISCL_;
      }
      float mv = (float)tt * DT_ * sa - sc;
      if (cnd == NT_ && mv >= 1.0f) cnd = tt;
    }
    cnd = min(cnd, NT_ - 1);                   // forced spike at last step
    idx1[((size_t)b << 10) + (jg << 6) + tid] = (uint8_t)cnd;
  }
}

// ---------------------------------------------------------------------------
// Layer-2: brute force. Block = (b,j), 4 waves split the i-range; lane = t.
// (unchanged, proven)
// ---------------------------------------------------------------------------
__global__ __launch_bounds__(256) void k_main2(const uint8_t* __restrict__ idx1,
                                               const float* __restrict__ W2,
                                               float* __restrict__ out) {
  __shared__ float wrow[F1_];
  __shared__ float tirow[F1_];
  __shared__ float part[4][3][64];
  const int blk = blockIdx.x;          // 640
  const int b   = blk / 10;
  const int j   = blk - b * 10;
  const int tid = threadIdx.x;
  const int lane = tid & 63, wvv = tid >> 6;

  const float*   w = W2  + (size_t)j * F1_;
  const uint8_t* h = idx1 + (size_t)b * F1_;
  for (int s = tid; s < F1_; s += 256) {
    wrow[s]  = w[s];
    tirow[s] = (float)h[s] * DT_;
  }
  __syncthreads();

  const float tl0 = (float)lane * DT_;
  const float tl1 = (float)(lane + 64) * DT_;
  const float tl2 = (float)(lane + 128) * DT_;
  float m0 = 0.f, m1 = 0.f, m2 = 0.f;
  const int i0 = wvv * 256;
#pragma unroll 4
  for (int i = i0; i < i0 + 256; ++i) {
    float tiv = tirow[i], ww = wrow[i];
    m0 = fmaf(ww, fmaxf(tl0 - tiv, 0.f), m0);
    m1 = fmaf(ww, fmaxf(tl1 - tiv, 0.f), m1);
    m2 = fmaf(ww, fmaxf(tl2 - tiv, 0.f), m2);
  }
  part[wvv][0][lane] = m0;
  part[wvv][1][lane] = m1;
  part[wvv][2][lane] = m2;
  __syncthreads();

  if (wvv == 0) {
    m0 = part[0][0][lane] + part[1][0][lane] + part[2][0][lane] + part[3][0][lane];
    m1 = part[0][1][lane] + part[1][1][lane] + part[2][1][lane] + part[3][1][lane];
    m2 = part[0][2][lane] + part[1][2][lane] + part[2][2][lane] + part[3][2][lane];
    unsigned long long b0 = __ballot(m0 >= 1.0f);
    unsigned long long b1 = __ballot(m1 >= 1.0f);
    unsigned long long b2 = __ballot(m2 >= 1.0f);
    b2 &= (1ull << 23) - 1;            // t <= 150
    b2 |= (1ull << 22);                // forced spike at t = 150
    int tres;
    if (b0)      tres = __ffsll((long long)b0) - 1;
    else if (b1) tres = 64 + __ffsll((long long)b1) - 1;
    else         tres = 128 + __ffsll((long long)b2) - 1;
    if (lane == 0) out[(size_t)b * F2_ + j] = (float)tres * DT_;
  }
}

}  // namespace

// ---------------------------------------------------------------------------
extern "C" void kernel_launch(void* const* d_in, const int* in_sizes, int n_in,
                              void* d_out, int out_size, void* d_ws, size_t ws_size,
                              hipStream_t stream) {
  const float* ti = (const float*)d_in[0];   // [64][1876]
  const float* W1 = (const float*)d_in[1];   // [1024][1876]
  const float* W2 = (const float*)d_in[2];   // [10][1024]
  float* out = (float*)d_out;                // [64][10]

  char* ws = (char*)d_ws;
  int4*     W1iT4 = (int4*)(ws + OFF_W1I4);
  uint16_t* koff  = (uint16_t*)(ws + OFF_KOFF);
  float*    tvs   = (float*)(ws + OFF_TV);
  uint8_t*  idx1  = (uint8_t*)(ws + OFF_IDX1);

  hipLaunchKernelGGL(k_prep,  dim3(NBLK_T + NBLK_R), dim3(256), 0, stream,
                     W1, ti, W1iT4, koff, tvs);
  hipLaunchKernelGGL(k_main1, dim3(1024), dim3(512), 0, stream,
                     koff, tvs, W1iT4, idx1);
  hipLaunchKernelGGL(k_main2, dim3(640),  dim3(256), 0, stream, idx1, W2, out);
}

// Round 20
// 69.180 us; speedup vs baseline: 1.0273x; 1.0017x over previous
//
#include <hip/hip_runtime.h>
#include <stdint.h>

namespace {

constexpr int   B_   = 64;
constexpr int   F0_  = 1876;
constexpr int   NI4_ = 469;       // 1876 / 4 exact
constexpr int   F1_  = 1024;
constexpr int   F2_  = 10;
constexpr int   NT_  = 151;
constexpr float DT_  = 0.02f;
constexpr float SCL_  = 1073741824.0f;      // 2^30 fixed-point scale
constexpr float ISCL_ = 1.0f / 1073741824.0f;

// workspace layout (bytes)
constexpr size_t OFF_W1I4 = 0;                     // 469*1024*16 = 7,684,096
constexpr size_t OFF_IDX1 = 7684096;               // 64*1024 u8  =    65,536

// ---------------------------------------------------------------------------
// k_prep: W1[j][i] f32 -> W1iT4[i4][j][4] int (rn(w*2^30)) — transpose only
// (rec side fused into k_main1 this round).
// ---------------------------------------------------------------------------
__global__ __launch_bounds__(256) void k_prep(const float* __restrict__ W1,
                                              int4* __restrict__ W1iT4) {
  __shared__ float tile[64][65];
  const int t  = threadIdx.x;
  const int bx = blockIdx.x;          // 480 = 30 i-tiles x 16 j-tiles
  const int i0 = (bx % 30) * 64;      // 0..1856
  const int j0 = (bx / 30) * 64;
  const int c = t & 63, r4 = t >> 6;
  for (int jj = r4; jj < 64; jj += 4) {
    int i = i0 + c;
    tile[c][jj] = (i < F0_) ? W1[(size_t)(j0 + jj) * F0_ + i] : 0.0f;
  }
  __syncthreads();
  for (int ii4 = r4; ii4 < 16; ii4 += 4) {
    int i4 = (i0 >> 2) + ii4;
    if (i4 < NI4_) {
      int4 v;
      v.x = __float2int_rn(tile[ii4 * 4 + 0][c] * SCL_);
      v.y = __float2int_rn(tile[ii4 * 4 + 1][c] * SCL_);
      v.z = __float2int_rn(tile[ii4 * 4 + 2][c] * SCL_);
      v.w = __float2int_rn(tile[ii4 * 4 + 3][c] * SCL_);
      W1iT4[(size_t)i4 * F1_ + j0 + c] = v;
    }
  }
}

// ---------------------------------------------------------------------------
// Layer 1 (r19 structure, rec fused): 1024 blocks = b*16 + jg (XCD = jg%8 ->
// ~1 MB W slice L2-fit), 512 threads = 8 waves; wave = 64 j (lane = j);
// waves split the 469-i4 range 8 ways.  ti read directly as WAVE-UNIFORM
// float4; bin k computed inline (VALU has headroom: r19 VALUBusy 38% under
// the DS wall).  Per element TWO ds_add_u32 into ONE shared bins[2][51][64]
// array (r18 lesson: never cross-array pointer offsets).  k wave-uniform ->
// stride-1 atomics, conflict-free by construction (r15-r19: 0 conflicts).
// int32 adds commute -> bit-deterministic; numerics identical to r19
// (absmax 0.0).  DS-atomic throughput is the measured wall (~7.4 cyc/
// wave-op == pipe limit; u64 vs 2xu32 A/B was null).
// Phase 2: tid<64 fused prefix+crossing.  LDS 26 KB.
// ---------------------------------------------------------------------------
__global__ __launch_bounds__(512, 8) void k_main1(const float* __restrict__ ti,
                                                  const int4* __restrict__ W1iT4,
                                                  uint8_t* __restrict__ idx1) {
  __shared__ int bins[2][51][64];   // [0]=A, [1]=C — one object, contiguous
  const int blk  = blockIdx.x;      // 1024
  const int b    = blk >> 4;
  const int jg   = blk & 15;
  const int tid  = threadIdx.x;
  const int lane = tid & 63;
  const int wv   = __builtin_amdgcn_readfirstlane(tid >> 6);  // 0..7

  {
    int4* p = (int4*)(&bins[0][0][0]);
    for (int s = tid; s < (2 * 51 * 64) / 4; s += 512)
      p[s] = make_int4(0, 0, 0, 0);
  }
  __syncthreads();

  // wave i4-split: 469 = 8*58 + 5
  const int cnt = 58 + (wv < 5 ? 1 : 0);
  const int g0  = wv * 58 + (wv < 5 ? wv : 5);

  const int4*  __restrict__ wp = W1iT4 + (jg << 6) + lane;   // + i4*1024
  const float* __restrict__ tb = ti + (size_t)b * F0_;       // uniform rows
  char* const binlane = (char*)(&bins[0][0][0]) + (lane << 2);

#define ELEM(a_, tv_) {                                                       \
    int k_ = (int)fminf(ceilf((tv_) * 50.0f), 50.0f);  /* ti >= 0 */          \
    int c_ = __float2int_rn((float)(a_) * (tv_));                             \
    int* cell = (int*)(binlane + (k_ << 8));                                  \
    atomicAdd(cell, (a_));                  /* ds_add_u32, binA */            \
    atomicAdd(cell + 51 * 64, c_);          /* binC: +13056 B, same array */ }

#pragma unroll 2
  for (int m = 0; m < cnt; ++m) {
    const int i4 = g0 + m;
    int4   wa  = wp[(size_t)i4 << 10];              // coalesced 1 KB/wave
    float4 tv4 = *(const float4*)(tb + i4 * 4);     // uniform broadcast
    ELEM(wa.x, tv4.x);
    ELEM(wa.y, tv4.y);
    ELEM(wa.z, tv4.z);
    ELEM(wa.w, tv4.w);
  }
#undef ELEM
  __syncthreads();

  // phase 2: tid < 64, thread owns j = jg*64 + tid. Fused prefix + crossing.
  if (tid < 64) {
    float sa = 0.f, sc = 0.f;
    int cnd = NT_;
#pragma unroll 1
    for (int tt = 0; tt < NT_; ++tt) {
      if (tt < 51) {
        sa += (float)bins[0][tt][tid] * ISCL_;
        sc += (float)bins[1][tt][tid] * ISCL_;
      }
      float mv = (float)tt * DT_ * sa - sc;
      if (cnd == NT_ && mv >= 1.0f) cnd = tt;
    }
    cnd = min(cnd, NT_ - 1);                   // forced spike at last step
    idx1[((size_t)b << 10) + (jg << 6) + tid] = (uint8_t)cnd;
  }
}

// ---------------------------------------------------------------------------
// Layer-2: block = (b,j), 4 waves split the i-range; lane = t.
// r19 lesson applied: W2[j][i] and idx1[b][i] are WAVE-UNIFORM in this
// layout -> read via uniform float4/uchar4 loads, convert h*DT inline
// (v_cvt_f32_ubyte). ZERO per-iter DS (was 512 ds_read/wave ~ 12 us).
// ---------------------------------------------------------------------------
__global__ __launch_bounds__(256) void k_main2(const uint8_t* __restrict__ idx1,
                                               const float* __restrict__ W2,
                                               float* __restrict__ out) {
  __shared__ float part[4][3][64];
  const int blk = blockIdx.x;          // 640
  const int b   = blk / 10;
  const int j   = blk - b * 10;
  const int tid = threadIdx.x;
  const int lane = tid & 63, wvv = tid >> 6;

  const float4*   __restrict__ w4 = (const float4*)(W2 + (size_t)j * F1_);
  const uint32_t* __restrict__ h4 = (const uint32_t*)(idx1 + ((size_t)b << 10));

  const float tl0 = (float)lane * DT_;
  const float tl1 = (float)(lane + 64) * DT_;
  const float tl2 = (float)(lane + 128) * DT_;
  float m0 = 0.f, m1 = 0.f, m2 = 0.f;
  const int q0 = wvv * 64;
#pragma unroll 4
  for (int q = q0; q < q0 + 64; ++q) {          // 4 i's per iter
    float4   w  = w4[q];                        // uniform
    uint32_t hh = h4[q];                        // uniform
#define E2(we_, sh_) {                                                        \
      float tiv = (float)((hh >> (sh_)) & 255u) * DT_;                        \
      m0 = fmaf((we_), fmaxf(tl0 - tiv, 0.f), m0);                            \
      m1 = fmaf((we_), fmaxf(tl1 - tiv, 0.f), m1);                            \
      m2 = fmaf((we_), fmaxf(tl2 - tiv, 0.f), m2); }
    E2(w.x, 0); E2(w.y, 8); E2(w.z, 16); E2(w.w, 24);
#undef E2
  }
  part[wvv][0][lane] = m0;
  part[wvv][1][lane] = m1;
  part[wvv][2][lane] = m2;
  __syncthreads();

  if (wvv == 0) {
    m0 = part[0][0][lane] + part[1][0][lane] + part[2][0][lane] + part[3][0][lane];
    m1 = part[0][1][lane] + part[1][1][lane] + part[2][1][lane] + part[3][1][lane];
    m2 = part[0][2][lane] + part[1][2][lane] + part[2][2][lane] + part[3][2][lane];
    unsigned long long b0 = __ballot(m0 >= 1.0f);
    unsigned long long b1 = __ballot(m1 >= 1.0f);
    unsigned long long b2 = __ballot(m2 >= 1.0f);
    b2 &= (1ull << 23) - 1;            // t <= 150
    b2 |= (1ull << 22);                // forced spike at t = 150
    int tres;
    if (b0)      tres = __ffsll((long long)b0) - 1;
    else if (b1) tres = 64 + __ffsll((long long)b1) - 1;
    else         tres = 128 + __ffsll((long long)b2) - 1;
    if (lane == 0) out[(size_t)b * F2_ + j] = (float)tres * DT_;
  }
}

}  // namespace

// ---------------------------------------------------------------------------
extern "C" void kernel_launch(void* const* d_in, const int* in_sizes, int n_in,
                              void* d_out, int out_size, void* d_ws, size_t ws_size,
                              hipStream_t stream) {
  const float* ti = (const float*)d_in[0];   // [64][1876]
  const float* W1 = (const float*)d_in[1];   // [1024][1876]
  const float* W2 = (const float*)d_in[2];   // [10][1024]
  float* out = (float*)d_out;                // [64][10]

  char* ws = (char*)d_ws;
  int4*    W1iT4 = (int4*)(ws + OFF_W1I4);
  uint8_t* idx1  = (uint8_t*)(ws + OFF_IDX1);

  hipLaunchKernelGGL(k_prep,  dim3(480),  dim3(256), 0, stream, W1, W1iT4);
  hipLaunchKernelGGL(k_main1, dim3(1024), dim3(512), 0, stream, ti, W1iT4, idx1);
  hipLaunchKernelGGL(k_main2, dim3(640),  dim3(256), 0, stream, idx1, W2, out);
}